// Round 7
// baseline (478.473 us; speedup 1.0000x reference)
//
#include <hip/hip_runtime.h>

#define DEVI static __device__ __forceinline__

typedef __attribute__((ext_vector_type(8))) short bf16x8;
typedef __attribute__((ext_vector_type(4))) float f32x4;

DEVI ushort f2bf(float f) {
  union { float f; unsigned u; } v; v.f = f;
  unsigned r = v.u + 0x7fffu + ((v.u >> 16) & 1u);
  return (ushort)(r >> 16);
}
DEVI float bf2f(ushort u) {
  union { unsigned u; float f; } v; v.u = ((unsigned)u) << 16;
  return v.f;
}

// B=16, C=256, CI=128, N=4096 (64x64), M=1024 (32x32)
// ---- workspace layout (bytes) ----
#define WS_XT    0ull                      // bf16 [16][4096][256]
#define WS_WCAT  33554432ull               // bf16 [256][256] rows 0-127 phi_w, 128-255 g_w
#define WS_PG    (WS_WCAT + 131072ull)     // f32  [16][128][128]
#define WS_RST   (WS_PG + 1048576ull)      // bf16 [16][256][256]
#define WS_S     (WS_RST + 2097152ull)     // f32  [16][256]
#define WS_WY    (WS_S + 16384ull)         // bf16 [16][256][4096]  (NCHW-aligned)
#define WS_SUM   (WS_WY + 33554432ull)     // f32 [256] sum + [256] sumsq
// phi/g (f32 [16][128][1024] each) overlay WY: dead before kwyT writes WY
#define WS_PHI   WS_WY
#define WS_G     (WS_WY + 8388608ull)

// ---------------- P: transpose x -> xT bf16, prep conv weights, zero accums -----
__global__ __launch_bounds__(256) void kprep(
    const float* __restrict__ x, const float* __restrict__ phw,
    const float* __restrict__ gww, char* __restrict__ ws) {
  __shared__ float tile[64 * 65];
  const int bid = blockIdx.x, t = threadIdx.x;
  if (bid < 4096) {
    const int b = bid >> 8, rem = bid & 255;
    const int c0 = (rem >> 6) * 64, n0 = (rem & 63) * 64;
    const float* xb = x + ((size_t)(b * 256 + c0)) * 4096 + n0;
#pragma unroll
    for (int it = 0; it < 4; ++it) {
      int ch = t + it * 256;
      int cr = ch >> 4, nf = ch & 15;
      float4 v = *(const float4*)(xb + (size_t)cr * 4096 + nf * 4);
      tile[cr * 65 + nf * 4 + 0] = v.x;
      tile[cr * 65 + nf * 4 + 1] = v.y;
      tile[cr * 65 + nf * 4 + 2] = v.z;
      tile[cr * 65 + nf * 4 + 3] = v.w;
    }
    __syncthreads();
    ushort* xT = (ushort*)(ws + WS_XT);
#pragma unroll
    for (int it = 0; it < 2; ++it) {
      int ch = t + it * 256;
      int rn = ch >> 3, jc = ch & 7;
      uint4 pk;
      pk.x = (unsigned)f2bf(tile[(jc * 8 + 0) * 65 + rn]) | ((unsigned)f2bf(tile[(jc * 8 + 1) * 65 + rn]) << 16);
      pk.y = (unsigned)f2bf(tile[(jc * 8 + 2) * 65 + rn]) | ((unsigned)f2bf(tile[(jc * 8 + 3) * 65 + rn]) << 16);
      pk.z = (unsigned)f2bf(tile[(jc * 8 + 4) * 65 + rn]) | ((unsigned)f2bf(tile[(jc * 8 + 5) * 65 + rn]) << 16);
      pk.w = (unsigned)f2bf(tile[(jc * 8 + 6) * 65 + rn]) | ((unsigned)f2bf(tile[(jc * 8 + 7) * 65 + rn]) << 16);
      *(uint4*)(xT + ((size_t)(b * 4096 + n0 + rn)) * 256 + c0 + jc * 8) = pk;
    }
  } else if (bid == 4096) {
    ushort* Wcat = (ushort*)(ws + WS_WCAT);
    for (int idx = t; idx < 65536; idx += 256) {
      int ci = idx >> 8, c = idx & 255;
      float v = (ci < 128) ? phw[ci * 256 + c] : gww[(ci - 128) * 256 + c];
      Wcat[idx] = f2bf(v);
    }
  } else if (bid == 4097) {
    float4 z = {0.f, 0.f, 0.f, 0.f};
    float4* st = (float4*)(ws + WS_SUM);
    if (t < 128) st[t] = z;
  } else {
    const int b = bid - 4098;  // 0..15: zero PG[b] (kpg32 K-split accumulates atomically)
    float4 z = {0.f, 0.f, 0.f, 0.f};
    float4* pg = (float4*)(ws + WS_PG + (size_t)b * 65536);
    for (int i = t; i < 4096; i += 256) pg[i] = z;
  }
}

// ------------- K1: phi/g conv (bf16 MFMA) + 2x2 maxpool + bias, store f32 [ci][m]
__global__ __launch_bounds__(256) void kconvpg(
    const float* __restrict__ phib, const float* __restrict__ gb,
    char* __restrict__ ws) {
  __shared__ __align__(16) char lds[49152];  // A: [128 n][64 c] 16KB, B: [256 ci][64 c] 32KB
  const int t = threadIdx.x;
  const int b = blockIdx.y, nb = blockIdx.x;
  const int n0 = nb * 128;
  const int lane = t & 63, wave = t >> 6;
  const int lr = lane & 15, lq = lane >> 4;
  const ushort* xT = (const ushort*)(ws + WS_XT) + ((size_t)(b * 4096 + n0)) * 256;
  const ushort* Wc = (const ushort*)(ws + WS_WCAT);

  f32x4 acc[8][4];
#pragma unroll
  for (int i = 0; i < 8; ++i)
#pragma unroll
    for (int j = 0; j < 4; ++j) acc[i][j] = (f32x4){0.f, 0.f, 0.f, 0.f};

  int4 ra[4], rb[8];
#pragma unroll
  for (int it = 0; it < 4; ++it) {
    int ch = t + it * 256, r = ch >> 3, jc = ch & 7;
    ra[it] = *(const int4*)(xT + (size_t)r * 256 + jc * 8);
  }
#pragma unroll
  for (int it = 0; it < 8; ++it) {
    int ch = t + it * 256, r = ch >> 3, jc = ch & 7;
    rb[it] = *(const int4*)(Wc + r * 256 + jc * 8);
  }
  const int swz = (lr & 7) << 4;

  for (int ks = 0; ks < 4; ++ks) {
#pragma unroll
    for (int it = 0; it < 4; ++it) {
      int ch = t + it * 256, r = ch >> 3, jc = ch & 7;
      *(int4*)(lds + r * 128 + ((jc * 16) ^ ((r & 7) << 4))) = ra[it];
    }
#pragma unroll
    for (int it = 0; it < 8; ++it) {
      int ch = t + it * 256, r = ch >> 3, jc = ch & 7;
      *(int4*)(lds + 16384 + r * 128 + ((jc * 16) ^ ((r & 7) << 4))) = rb[it];
    }
    __syncthreads();
    if (ks < 3) {
#pragma unroll
      for (int it = 0; it < 4; ++it) {
        int ch = t + it * 256, r = ch >> 3, jc = ch & 7;
        ra[it] = *(const int4*)(xT + (size_t)r * 256 + (ks + 1) * 64 + jc * 8);
      }
#pragma unroll
      for (int it = 0; it < 8; ++it) {
        int ch = t + it * 256, r = ch >> 3, jc = ch & 7;
        rb[it] = *(const int4*)(Wc + r * 256 + (ks + 1) * 64 + jc * 8);
      }
    }
#pragma unroll
    for (int k2 = 0; k2 < 2; ++k2) {
      const int kb = k2 * 64 + lq * 16;
      bf16x8 bfr[4];
#pragma unroll
      for (int j = 0; j < 4; ++j) {
        int bc = wave * 64 + j * 16 + lr;
        bfr[j] = *(const bf16x8*)(lds + 16384 + bc * 128 + (kb ^ swz));
      }
#pragma unroll
      for (int i = 0; i < 8; ++i) {
        int arw = i * 16 + lr;
        bf16x8 af = *(const bf16x8*)(lds + arw * 128 + (kb ^ swz));
#pragma unroll
        for (int j = 0; j < 4; ++j)
          acc[i][j] = __builtin_amdgcn_mfma_f32_16x16x32_bf16(af, bfr[j], acc[i][j], 0, 0, 0);
      }
    }
    __syncthreads();
  }
  // epilogue: pool (ln,ln+1)x(ln+64,ln+65) + bias -> LDS [256ci][36] f32, then coalesced store
  float* pool = (float*)lds;
#pragma unroll
  for (int j = 0; j < 4; ++j) {
    int cir = wave * 64 + j * 16 + lr;
    float bias = (cir < 128) ? phib[cir] : gb[cir - 128];
#pragma unroll
    for (int i = 0; i < 4; ++i) {
      f32x4 lo = acc[i][j], hi = acc[i + 4][j];
      float m0 = fmaxf(fmaxf(lo[0], lo[1]), fmaxf(hi[0], hi[1])) + bias;
      float m1 = fmaxf(fmaxf(lo[2], lo[3]), fmaxf(hi[2], hi[3])) + bias;
      pool[cir * 36 + i * 8 + lq * 2] = m0;
      pool[cir * 36 + i * 8 + lq * 2 + 1] = m1;
    }
  }
  __syncthreads();
  const int rr_ = t >> 3, chk = t & 7;
#pragma unroll
  for (int pass = 0; pass < 8; ++pass) {
    int ci = pass * 32 + rr_;
    float4 v = *(const float4*)(pool + ci * 36 + chk * 4);
    float* dst = (ci < 128)
        ? ((float*)(ws + WS_PHI) + ((size_t)(b * 128 + ci)) * 1024)
        : ((float*)(ws + WS_G) + ((size_t)(b * 128 + ci - 128)) * 1024);
    *(float4*)(dst + nb * 32 + chk * 4) = v;
  }
}

// ------------- K2a: PG[b][ci][cj] += sum_m phi[ci][m]*g[cj][m]  (fp32, K-split) --
__global__ __launch_bounds__(256) void kpg32(char* __restrict__ ws) {
  __shared__ float lphi[32 * 65];
  __shared__ float lgd[32 * 65];
  const int t = threadIdx.x, b = blockIdx.y, kz = blockIdx.z;
  const int cib = blockIdx.x >> 2, cjb = blockIdx.x & 3;
  const int ci_l = t >> 5, cj_l = t & 31;
  const float* phi = (const float*)(ws + WS_PHI) + ((size_t)(b * 128 + cib * 32)) * 1024;
  const float* gg = (const float*)(ws + WS_G) + ((size_t)(b * 128 + cjb * 32)) * 1024;
  float acc[4] = {0.f, 0.f, 0.f, 0.f};
  for (int kc = kz * 4; kc < kz * 4 + 4; ++kc) {
#pragma unroll
    for (int it = 0; it < 8; ++it) {
      int fi = t + it * 256;
      int r = fi >> 6, c = fi & 63;
      lphi[r * 65 + c] = phi[(size_t)r * 1024 + kc * 64 + c];
      lgd[r * 65 + c] = gg[(size_t)r * 1024 + kc * 64 + c];
    }
    __syncthreads();
#pragma unroll 8
    for (int k = 0; k < 64; ++k) {
      float gv = lgd[cj_l * 65 + k];
#pragma unroll
      for (int p = 0; p < 4; ++p)
        acc[p] += lphi[(ci_l * 4 + p) * 65 + k] * gv;
    }
    __syncthreads();
  }
  float* PG = (float*)(ws + WS_PG) + (size_t)b * 16384;
#pragma unroll
  for (int p = 0; p < 4; ++p)
    atomicAdd(&PG[(cib * 32 + ci_l * 4 + p) * 128 + cjb * 32 + cj_l], acc[p]);
}

// ------------- K2b: fused Qt -> Rst -> s, all fp32 VALU --------------------------
__global__ __launch_bounds__(256) void kmid(
    const float* __restrict__ thw, const float* __restrict__ thb,
    const float* __restrict__ wbias, const float* __restrict__ www,
    char* __restrict__ ws) {
  __shared__ __align__(16) char smid[49920];
  float* PGc = (float*)smid;             // [128][33] (phase 1)
  float* Wws = (float*)(smid + 16896);   // [32][129] (phase 1)
  float* Qts = (float*)(smid + 33408);   // [32][129]
  float* thws = (float*)smid;            // [128][65] (phase 2, overlays PGc+Wws)
  const int t = threadIdx.x, b = blockIdx.y, cblk = blockIdx.x;
  const int c_l = t >> 3, q = t & 7;
  const float* PGg = (const float*)(ws + WS_PG) + (size_t)b * 16384;

#pragma unroll
  for (int it = 0; it < 16; ++it) {
    int fi = t + it * 256;
    int r = fi >> 7, j = fi & 127;
    Wws[r * 129 + j] = www[(cblk * 32 + r) * 128 + j];
  }
  float qacc[16];
#pragma unroll
  for (int i = 0; i < 16; ++i) qacc[i] = 0.f;

  for (int jc = 0; jc < 4; ++jc) {
#pragma unroll
    for (int it = 0; it < 16; ++it) {
      int fi = t + it * 256;
      int i = fi >> 5, jl = fi & 31;
      PGc[i * 33 + jl] = PGg[i * 128 + jc * 32 + jl];
    }
    __syncthreads();
#pragma unroll
    for (int iq = 0; iq < 16; ++iq) {
      int i = iq * 8 + q;
      float a = 0.f;
#pragma unroll 8
      for (int jl = 0; jl < 32; ++jl)
        a += Wws[c_l * 129 + jc * 32 + jl] * PGc[i * 33 + jl];
      qacc[iq] += a;
    }
    __syncthreads();
  }
  const float inv = 1.0f / 1024.0f;
#pragma unroll
  for (int iq = 0; iq < 16; ++iq) Qts[c_l * 129 + iq * 8 + q] = qacc[iq] * inv;
  __syncthreads();
  if (t < 32) {
    float sv = wbias[cblk * 32 + t];
    for (int i = 0; i < 128; ++i) sv += thb[i] * Qts[t * 129 + i];
    ((float*)(ws + WS_S))[b * 256 + cblk * 32 + t] = sv;
  }
  ushort* Rstb = (ushort*)(ws + WS_RST) + (size_t)b * 65536;
  for (int cpc = 0; cpc < 4; ++cpc) {
#pragma unroll
    for (int it = 0; it < 32; ++it) {
      int fi = t + it * 256;
      int i = fi >> 6, cp = fi & 63;
      thws[i * 65 + cp] = thw[i * 256 + cpc * 64 + cp];
    }
    __syncthreads();
#pragma unroll
    for (int k = 0; k < 8; ++k) {
      int cpl = q * 8 + k;
      float a = 0.f;
#pragma unroll 8
      for (int i = 0; i < 128; ++i)
        a += Qts[c_l * 129 + i] * thws[i * 65 + cpl];
      Rstb[(cblk * 32 + c_l) * 256 + cpc * 64 + cpl] = f2bf(a);
    }
    __syncthreads();
  }
}

// ------------- K3: wy[b][c][n] = Rst[c][:].xT[n][:] + s[c]  (A=Rst, B=xT) --------
// coalesced [c][n] bf16 store via LDS transpose; fused channel stats
__global__ __launch_bounds__(256) void kwyT(char* __restrict__ ws) {
  __shared__ __align__(16) char lds[40960];  // A Rst [256][64k] 32KB + B xT [64n][64k] 8KB
  const int t = threadIdx.x;
  const int b = blockIdx.y, nb = blockIdx.x;  // nb 0..63
  const int n0 = nb * 64;
  const int lane = t & 63, wave = t >> 6;
  const int lr = lane & 15, lq = lane >> 4;
  const ushort* xT = (const ushort*)(ws + WS_XT) + ((size_t)(b * 4096 + n0)) * 256;
  const ushort* Rst = (const ushort*)(ws + WS_RST) + (size_t)b * 65536;

  f32x4 acc[4][4];  // i: c-tile (wave*64+i*16), j: n-tile (j*16)
#pragma unroll
  for (int i = 0; i < 4; ++i)
#pragma unroll
    for (int j = 0; j < 4; ++j) acc[i][j] = (f32x4){0.f, 0.f, 0.f, 0.f};

  int4 ra[8], rb[2];
#pragma unroll
  for (int it = 0; it < 8; ++it) {
    int ch = t + it * 256, r = ch >> 3, jc = ch & 7;
    ra[it] = *(const int4*)(Rst + r * 256 + jc * 8);
  }
#pragma unroll
  for (int it = 0; it < 2; ++it) {
    int ch = t + it * 256, r = ch >> 3, jc = ch & 7;
    rb[it] = *(const int4*)(xT + (size_t)r * 256 + jc * 8);
  }

  for (int ks = 0; ks < 4; ++ks) {
#pragma unroll
    for (int it = 0; it < 8; ++it) {
      int ch = t + it * 256, r = ch >> 3, jc = ch & 7;
      *(int4*)(lds + r * 128 + ((jc * 16) ^ ((r & 7) << 4))) = ra[it];
    }
#pragma unroll
    for (int it = 0; it < 2; ++it) {
      int ch = t + it * 256, r = ch >> 3, jc = ch & 7;
      *(int4*)(lds + 32768 + r * 128 + ((jc * 16) ^ ((r & 7) << 4))) = rb[it];
    }
    __syncthreads();
    if (ks < 3) {
#pragma unroll
      for (int it = 0; it < 8; ++it) {
        int ch = t + it * 256, r = ch >> 3, jc = ch & 7;
        ra[it] = *(const int4*)(Rst + r * 256 + (ks + 1) * 64 + jc * 8);
      }
#pragma unroll
      for (int it = 0; it < 2; ++it) {
        int ch = t + it * 256, r = ch >> 3, jc = ch & 7;
        rb[it] = *(const int4*)(xT + (size_t)r * 256 + (ks + 1) * 64 + jc * 8);
      }
    }
#pragma unroll
    for (int k2 = 0; k2 < 2; ++k2) {
      const int kb = k2 * 64 + lq * 16;
      bf16x8 bfr[4];
#pragma unroll
      for (int j = 0; j < 4; ++j) {
        int rn = j * 16 + lr;
        bfr[j] = *(const bf16x8*)(lds + 32768 + rn * 128 + (kb ^ ((rn & 7) << 4)));
      }
#pragma unroll
      for (int i = 0; i < 4; ++i) {
        int rc = wave * 64 + i * 16 + lr;
        bf16x8 af = *(const bf16x8*)(lds + rc * 128 + (kb ^ ((rc & 7) << 4)));
#pragma unroll
        for (int j = 0; j < 4; ++j)
          acc[i][j] = __builtin_amdgcn_mfma_f32_16x16x32_bf16(af, bfr[j], acc[i][j], 0, 0, 0);
      }
    }
    __syncthreads();
  }
  // stage tile to LDS bf16 [256 c][72] (pad keeps 16B align, spreads banks)
  ushort* po = (ushort*)lds;
#pragma unroll
  for (int i = 0; i < 4; ++i)
#pragma unroll
    for (int j = 0; j < 4; ++j)
#pragma unroll
      for (int rr = 0; rr < 4; ++rr) {
        int c_ = wave * 64 + i * 16 + lq * 4 + rr;
        po[c_ * 72 + j * 16 + lr] = f2bf(acc[i][j][rr]);
      }
  __syncthreads();
  const float* sarr = (const float*)(ws + WS_S) + b * 256;
  ushort* wyb = (ushort*)(ws + WS_WY) + (size_t)b * 1048576;  // [256][4096]
  float* gsum = (float*)(ws + WS_SUM);
  float* gsq = gsum + 256;
  const int rr_ = t >> 3, chk = t & 7;
#pragma unroll
  for (int pass = 0; pass < 8; ++pass) {
    int c = pass * 32 + rr_;
    int4 v = *(const int4*)(po + c * 72 + chk * 8);
    float sv = sarr[c];
    unsigned w[4] = {(unsigned)v.x, (unsigned)v.y, (unsigned)v.z, (unsigned)v.w};
    float s1 = 0.f, s2 = 0.f;
    unsigned o[4];
#pragma unroll
    for (int q = 0; q < 4; ++q) {
      float f0 = bf2f((ushort)(w[q] & 0xffffu)) + sv;
      float f1 = bf2f((ushort)(w[q] >> 16)) + sv;
      s1 += f0 + f1;
      s2 += f0 * f0 + f1 * f1;
      o[q] = (unsigned)f2bf(f0) | ((unsigned)f2bf(f1) << 16);
    }
    int4 ov;
    ov.x = (int)o[0]; ov.y = (int)o[1]; ov.z = (int)o[2]; ov.w = (int)o[3];
    *(int4*)(wyb + (size_t)c * 4096 + n0 + chk * 8) = ov;
    s1 += __shfl_xor(s1, 1); s1 += __shfl_xor(s1, 2); s1 += __shfl_xor(s1, 4);
    s2 += __shfl_xor(s2, 1); s2 += __shfl_xor(s2, 2); s2 += __shfl_xor(s2, 4);
    if (chk == 0) {
      atomicAdd(&gsum[c], s1);
      atomicAdd(&gsq[c], s2);
    }
  }
}

// ------------- K5: out[b][c][n] = wy[c][n]*scale[c] + shift[c] + x[c][n] ---------
__global__ __launch_bounds__(256) void kout(
    const float* __restrict__ x, const float* __restrict__ gamma,
    const float* __restrict__ beta, const char* __restrict__ ws,
    float* __restrict__ out) {
  __shared__ float scaleL[256], shiftL[256];
  const int t = threadIdx.x;
  const int b = blockIdx.y, blk = blockIdx.x;
  {
    const float* gsum = (const float*)(ws + WS_SUM);
    float sm = gsum[t], sq = gsum[256 + t];
    float mean = sm * (1.0f / 65536.0f);
    float var = sq * (1.0f / 65536.0f) - mean * mean;
    float rs = rsqrtf(var + 1e-5f);
    float sc = gamma[t] * rs;
    scaleL[t] = sc;
    shiftL[t] = beta[t] - mean * sc;
  }
  __syncthreads();
  const ushort* wyb = (const ushort*)(ws + WS_WY) + (size_t)b * 1048576;
  const float* xb = x + (size_t)b * 1048576;
  float* ob = out + (size_t)b * 1048576;
#pragma unroll
  for (int it = 0; it < 8; ++it) {
    int idx = blk * 8192 + it * 1024 + t * 4;
    int c = idx >> 12;
    uint2 wv = *(const uint2*)(wyb + idx);
    float4 xv = *(const float4*)(xb + idx);
    float sc = scaleL[c], sh = shiftL[c];
    float4 ov;
    ov.x = bf2f((ushort)(wv.x & 0xffffu)) * sc + sh + xv.x;
    ov.y = bf2f((ushort)(wv.x >> 16)) * sc + sh + xv.y;
    ov.z = bf2f((ushort)(wv.y & 0xffffu)) * sc + sh + xv.z;
    ov.w = bf2f((ushort)(wv.y >> 16)) * sc + sh + xv.w;
    *(float4*)(ob + idx) = ov;
  }
}

extern "C" void kernel_launch(void* const* d_in, const int* in_sizes, int n_in,
                              void* d_out, int out_size, void* d_ws, size_t ws_size,
                              hipStream_t stream) {
  const float* x = (const float*)d_in[0];
  const float* thw = (const float*)d_in[1];
  const float* thb = (const float*)d_in[2];
  const float* phw = (const float*)d_in[3];
  const float* phb = (const float*)d_in[4];
  const float* gw = (const float*)d_in[5];
  const float* gb = (const float*)d_in[6];
  const float* www = (const float*)d_in[7];
  const float* wwb = (const float*)d_in[8];
  const float* gamma = (const float*)d_in[9];
  const float* beta = (const float*)d_in[10];
  char* ws = (char*)d_ws;
  float* out = (float*)d_out;

  kprep<<<dim3(4114), dim3(256), 0, stream>>>(x, phw, gw, ws);
  kconvpg<<<dim3(32, 16), dim3(256), 0, stream>>>(phb, gb, ws);
  kpg32<<<dim3(16, 16, 4), dim3(256), 0, stream>>>(ws);
  kmid<<<dim3(8, 16), dim3(256), 0, stream>>>(thw, thb, wwb, www, ws);
  kwyT<<<dim3(64, 16), dim3(256), 0, stream>>>(ws);
  kout<<<dim3(128, 16), dim3(256), 0, stream>>>(x, gamma, beta, ws, out);
}

// Round 8
// 433.141 us; speedup vs baseline: 1.1047x; 1.1047x over previous
//
#include <hip/hip_runtime.h>

#define DEVI static __device__ __forceinline__

typedef __attribute__((ext_vector_type(8))) short bf16x8;
typedef __attribute__((ext_vector_type(4))) float f32x4;

DEVI ushort f2bf(float f) {
  union { float f; unsigned u; } v; v.f = f;
  unsigned r = v.u + 0x7fffu + ((v.u >> 16) & 1u);
  return (ushort)(r >> 16);
}
DEVI float bf2f(ushort u) {
  union { unsigned u; float f; } v; v.u = ((unsigned)u) << 16;
  return v.f;
}

// B=16, C=256, CI=128, N=4096 (64x64), M=1024 (32x32)
// ---- workspace layout (bytes); peak use 66.0 MB ----
#define WS_XT    0ull                      // bf16 [16][4096][256]; per-block stat partials
                                           // are written into each kwyT block's OWN slice
                                           // after its last xT read (no aliasing).
#define WS_WCAT  33554432ull               // bf16 [256][256]; dead after kconvpg
#define WS_RST   33554432ull               // bf16 [16][256][256]; overlays WCAT (kmid->kwyT)
#define WS_S     35651584ull               // f32  [16][256]
#define WS_SUM   35667968ull               // f32  [256] sum + [256] sumsq
#define WS_WY    35672064ull               // bf16 [16][256][4096]
// overlays inside WY (dead before kwyT writes WY):
#define WS_PHI   WS_WY                     // f32 [16][128][1024]
#define WS_G     (WS_WY + 8388608ull)      // f32 [16][128][1024]
#define WS_PG    (WS_WY + 16777216ull)     // f32 [4 kz][16][128][128] (K-split parts)

// ---------------- P: transpose x -> xT bf16, prep conv weights, zero SUM --------
__global__ __launch_bounds__(256) void kprep(
    const float* __restrict__ x, const float* __restrict__ phw,
    const float* __restrict__ gww, char* __restrict__ ws) {
  __shared__ float tile[64 * 65];
  const int bid = blockIdx.x, t = threadIdx.x;
  if (bid < 4096) {
    const int b = bid >> 8, rem = bid & 255;
    const int c0 = (rem >> 6) * 64, n0 = (rem & 63) * 64;
    const float* xb = x + ((size_t)(b * 256 + c0)) * 4096 + n0;
#pragma unroll
    for (int it = 0; it < 4; ++it) {
      int ch = t + it * 256;
      int cr = ch >> 4, nf = ch & 15;
      float4 v = *(const float4*)(xb + (size_t)cr * 4096 + nf * 4);
      tile[cr * 65 + nf * 4 + 0] = v.x;
      tile[cr * 65 + nf * 4 + 1] = v.y;
      tile[cr * 65 + nf * 4 + 2] = v.z;
      tile[cr * 65 + nf * 4 + 3] = v.w;
    }
    __syncthreads();
    ushort* xT = (ushort*)(ws + WS_XT);
#pragma unroll
    for (int it = 0; it < 2; ++it) {
      int ch = t + it * 256;
      int rn = ch >> 3, jc = ch & 7;
      uint4 pk;
      pk.x = (unsigned)f2bf(tile[(jc * 8 + 0) * 65 + rn]) | ((unsigned)f2bf(tile[(jc * 8 + 1) * 65 + rn]) << 16);
      pk.y = (unsigned)f2bf(tile[(jc * 8 + 2) * 65 + rn]) | ((unsigned)f2bf(tile[(jc * 8 + 3) * 65 + rn]) << 16);
      pk.z = (unsigned)f2bf(tile[(jc * 8 + 4) * 65 + rn]) | ((unsigned)f2bf(tile[(jc * 8 + 5) * 65 + rn]) << 16);
      pk.w = (unsigned)f2bf(tile[(jc * 8 + 6) * 65 + rn]) | ((unsigned)f2bf(tile[(jc * 8 + 7) * 65 + rn]) << 16);
      *(uint4*)(xT + ((size_t)(b * 4096 + n0 + rn)) * 256 + c0 + jc * 8) = pk;
    }
  } else if (bid == 4096) {
    ushort* Wcat = (ushort*)(ws + WS_WCAT);
    for (int idx = t; idx < 65536; idx += 256) {
      int ci = idx >> 8, c = idx & 255;
      float v = (ci < 128) ? phw[ci * 256 + c] : gww[(ci - 128) * 256 + c];
      Wcat[idx] = f2bf(v);
    }
  } else {
    float4 z = {0.f, 0.f, 0.f, 0.f};
    float4* st = (float4*)(ws + WS_SUM);
    if (t < 128) st[t] = z;
  }
}

// ------------- K1: phi/g conv (bf16 MFMA) + 2x2 maxpool + bias, store f32 [ci][m]
__global__ __launch_bounds__(256) void kconvpg(
    const float* __restrict__ phib, const float* __restrict__ gb,
    char* __restrict__ ws) {
  __shared__ __align__(16) char lds[49152];  // A: [128 n][64 c] 16KB, B: [256 ci][64 c] 32KB
  const int t = threadIdx.x;
  const int b = blockIdx.y, nb = blockIdx.x;
  const int n0 = nb * 128;
  const int lane = t & 63, wave = t >> 6;
  const int lr = lane & 15, lq = lane >> 4;
  const ushort* xT = (const ushort*)(ws + WS_XT) + ((size_t)(b * 4096 + n0)) * 256;
  const ushort* Wc = (const ushort*)(ws + WS_WCAT);

  f32x4 acc[8][4];
#pragma unroll
  for (int i = 0; i < 8; ++i)
#pragma unroll
    for (int j = 0; j < 4; ++j) acc[i][j] = (f32x4){0.f, 0.f, 0.f, 0.f};

  int4 ra[4], rb[8];
#pragma unroll
  for (int it = 0; it < 4; ++it) {
    int ch = t + it * 256, r = ch >> 3, jc = ch & 7;
    ra[it] = *(const int4*)(xT + (size_t)r * 256 + jc * 8);
  }
#pragma unroll
  for (int it = 0; it < 8; ++it) {
    int ch = t + it * 256, r = ch >> 3, jc = ch & 7;
    rb[it] = *(const int4*)(Wc + r * 256 + jc * 8);
  }
  const int swz = (lr & 7) << 4;

  for (int ks = 0; ks < 4; ++ks) {
#pragma unroll
    for (int it = 0; it < 4; ++it) {
      int ch = t + it * 256, r = ch >> 3, jc = ch & 7;
      *(int4*)(lds + r * 128 + ((jc * 16) ^ ((r & 7) << 4))) = ra[it];
    }
#pragma unroll
    for (int it = 0; it < 8; ++it) {
      int ch = t + it * 256, r = ch >> 3, jc = ch & 7;
      *(int4*)(lds + 16384 + r * 128 + ((jc * 16) ^ ((r & 7) << 4))) = rb[it];
    }
    __syncthreads();
    if (ks < 3) {
#pragma unroll
      for (int it = 0; it < 4; ++it) {
        int ch = t + it * 256, r = ch >> 3, jc = ch & 7;
        ra[it] = *(const int4*)(xT + (size_t)r * 256 + (ks + 1) * 64 + jc * 8);
      }
#pragma unroll
      for (int it = 0; it < 8; ++it) {
        int ch = t + it * 256, r = ch >> 3, jc = ch & 7;
        rb[it] = *(const int4*)(Wc + r * 256 + (ks + 1) * 64 + jc * 8);
      }
    }
#pragma unroll
    for (int k2 = 0; k2 < 2; ++k2) {
      const int kb = k2 * 64 + lq * 16;
      bf16x8 bfr[4];
#pragma unroll
      for (int j = 0; j < 4; ++j) {
        int bc = wave * 64 + j * 16 + lr;
        bfr[j] = *(const bf16x8*)(lds + 16384 + bc * 128 + (kb ^ swz));
      }
#pragma unroll
      for (int i = 0; i < 8; ++i) {
        int arw = i * 16 + lr;
        bf16x8 af = *(const bf16x8*)(lds + arw * 128 + (kb ^ swz));
#pragma unroll
        for (int j = 0; j < 4; ++j)
          acc[i][j] = __builtin_amdgcn_mfma_f32_16x16x32_bf16(af, bfr[j], acc[i][j], 0, 0, 0);
      }
    }
    __syncthreads();
  }
  // epilogue: pool (ln,ln+1)x(ln+64,ln+65) + bias -> LDS [256ci][36] f32, then coalesced store
  float* pool = (float*)lds;
#pragma unroll
  for (int j = 0; j < 4; ++j) {
    int cir = wave * 64 + j * 16 + lr;
    float bias = (cir < 128) ? phib[cir] : gb[cir - 128];
#pragma unroll
    for (int i = 0; i < 4; ++i) {
      f32x4 lo = acc[i][j], hi = acc[i + 4][j];
      float m0 = fmaxf(fmaxf(lo[0], lo[1]), fmaxf(hi[0], hi[1])) + bias;
      float m1 = fmaxf(fmaxf(lo[2], lo[3]), fmaxf(hi[2], hi[3])) + bias;
      pool[cir * 36 + i * 8 + lq * 2] = m0;
      pool[cir * 36 + i * 8 + lq * 2 + 1] = m1;
    }
  }
  __syncthreads();
  const int rr_ = t >> 3, chk = t & 7;
#pragma unroll
  for (int pass = 0; pass < 8; ++pass) {
    int ci = pass * 32 + rr_;
    float4 v = *(const float4*)(pool + ci * 36 + chk * 4);
    float* dst = (ci < 128)
        ? ((float*)(ws + WS_PHI) + ((size_t)(b * 128 + ci)) * 1024)
        : ((float*)(ws + WS_G) + ((size_t)(b * 128 + ci - 128)) * 1024);
    *(float4*)(dst + nb * 32 + chk * 4) = v;
  }
}

// ------------- K2a: PG_part[kz][b][ci][cj] = sum_m(kz slice) phi*g  (no atomics) -
__global__ __launch_bounds__(256) void kpg32(char* __restrict__ ws) {
  __shared__ float lphi[32 * 65];
  __shared__ float lgd[32 * 65];
  const int t = threadIdx.x, b = blockIdx.y, kz = blockIdx.z;
  const int cib = blockIdx.x >> 2, cjb = blockIdx.x & 3;
  const int ci_l = t >> 5, cj_l = t & 31;
  const float* phi = (const float*)(ws + WS_PHI) + ((size_t)(b * 128 + cib * 32)) * 1024;
  const float* gg = (const float*)(ws + WS_G) + ((size_t)(b * 128 + cjb * 32)) * 1024;
  float acc[4] = {0.f, 0.f, 0.f, 0.f};
  for (int kc = kz * 4; kc < kz * 4 + 4; ++kc) {
#pragma unroll
    for (int it = 0; it < 8; ++it) {
      int fi = t + it * 256;
      int r = fi >> 6, c = fi & 63;
      lphi[r * 65 + c] = phi[(size_t)r * 1024 + kc * 64 + c];
      lgd[r * 65 + c] = gg[(size_t)r * 1024 + kc * 64 + c];
    }
    __syncthreads();
#pragma unroll 8
    for (int k = 0; k < 64; ++k) {
      float gv = lgd[cj_l * 65 + k];
#pragma unroll
      for (int p = 0; p < 4; ++p)
        acc[p] += lphi[(ci_l * 4 + p) * 65 + k] * gv;
    }
    __syncthreads();
  }
  float* PG = (float*)(ws + WS_PG) + (size_t)kz * 262144 + (size_t)b * 16384;
#pragma unroll
  for (int p = 0; p < 4; ++p)
    PG[(cib * 32 + ci_l * 4 + p) * 128 + cjb * 32 + cj_l] = acc[p];
}

// ------------- K2b: fused Qt -> Rst -> s, fp32 VALU; sums the 4 PG parts ---------
__global__ __launch_bounds__(256) void kmid(
    const float* __restrict__ thw, const float* __restrict__ thb,
    const float* __restrict__ wbias, const float* __restrict__ www,
    char* __restrict__ ws) {
  __shared__ __align__(16) char smid[49920];
  float* PGc = (float*)smid;             // [128][33] (phase 1)
  float* Wws = (float*)(smid + 16896);   // [32][129] (phase 1)
  float* Qts = (float*)(smid + 33408);   // [32][129]
  float* thws = (float*)smid;            // [128][65] (phase 2, overlays PGc+Wws)
  const int t = threadIdx.x, b = blockIdx.y, cblk = blockIdx.x;
  const int c_l = t >> 3, q = t & 7;
  const float* PG0 = (const float*)(ws + WS_PG) + (size_t)b * 16384;

#pragma unroll
  for (int it = 0; it < 16; ++it) {
    int fi = t + it * 256;
    int r = fi >> 7, j = fi & 127;
    Wws[r * 129 + j] = www[(cblk * 32 + r) * 128 + j];
  }
  float qacc[16];
#pragma unroll
  for (int i = 0; i < 16; ++i) qacc[i] = 0.f;

  for (int jc = 0; jc < 4; ++jc) {
#pragma unroll
    for (int it = 0; it < 16; ++it) {
      int fi = t + it * 256;
      int i = fi >> 5, jl = fi & 31;
      int idx = i * 128 + jc * 32 + jl;
      PGc[i * 33 + jl] = PG0[idx] + PG0[262144 + idx] + PG0[524288 + idx] + PG0[786432 + idx];
    }
    __syncthreads();
#pragma unroll
    for (int iq = 0; iq < 16; ++iq) {
      int i = iq * 8 + q;
      float a = 0.f;
#pragma unroll 8
      for (int jl = 0; jl < 32; ++jl)
        a += Wws[c_l * 129 + jc * 32 + jl] * PGc[i * 33 + jl];
      qacc[iq] += a;
    }
    __syncthreads();
  }
  const float inv = 1.0f / 1024.0f;
#pragma unroll
  for (int iq = 0; iq < 16; ++iq) Qts[c_l * 129 + iq * 8 + q] = qacc[iq] * inv;
  __syncthreads();
  if (t < 32) {
    float sv = wbias[cblk * 32 + t];
    for (int i = 0; i < 128; ++i) sv += thb[i] * Qts[t * 129 + i];
    ((float*)(ws + WS_S))[b * 256 + cblk * 32 + t] = sv;
  }
  ushort* Rstb = (ushort*)(ws + WS_RST) + (size_t)b * 65536;
  for (int cpc = 0; cpc < 4; ++cpc) {
#pragma unroll
    for (int it = 0; it < 32; ++it) {
      int fi = t + it * 256;
      int i = fi >> 6, cp = fi & 63;
      thws[i * 65 + cp] = thw[i * 256 + cpc * 64 + cp];
    }
    __syncthreads();
#pragma unroll
    for (int k = 0; k < 8; ++k) {
      int cpl = q * 8 + k;
      float a = 0.f;
#pragma unroll 8
      for (int i = 0; i < 128; ++i)
        a += Qts[c_l * 129 + i] * thws[i * 65 + cpl];
      Rstb[(cblk * 32 + c_l) * 256 + cpc * 64 + cpl] = f2bf(a);
    }
    __syncthreads();
  }
}

// ------------- K3: wy[b][c][n] = Rst[c][:].xT[n][:] + s[c]  (A=Rst, B=xT) --------
// coalesced [c][n] store; per-block channel stats -> one float2[256] record
// written into this block's OWN (dead) xT slice. NO global atomics.
__global__ __launch_bounds__(256) void kwyT(char* __restrict__ ws) {
  __shared__ __align__(16) char lds[40960];  // loop: Rst 32KB + xT 8KB; epi: po 36KB + sls 2KB
  const int t = threadIdx.x;
  const int b = blockIdx.y, nb = blockIdx.x;  // nb 0..63
  const int n0 = nb * 64;
  const int lane = t & 63, wave = t >> 6;
  const int lr = lane & 15, lq = lane >> 4;
  const ushort* xT = (const ushort*)(ws + WS_XT) + ((size_t)(b * 4096 + n0)) * 256;
  const ushort* Rst = (const ushort*)(ws + WS_RST) + (size_t)b * 65536;

  f32x4 acc[4][4];  // i: c-tile (wave*64+i*16), j: n-tile (j*16)
#pragma unroll
  for (int i = 0; i < 4; ++i)
#pragma unroll
    for (int j = 0; j < 4; ++j) acc[i][j] = (f32x4){0.f, 0.f, 0.f, 0.f};

  int4 ra[8], rb[2];
#pragma unroll
  for (int it = 0; it < 8; ++it) {
    int ch = t + it * 256, r = ch >> 3, jc = ch & 7;
    ra[it] = *(const int4*)(Rst + r * 256 + jc * 8);
  }
#pragma unroll
  for (int it = 0; it < 2; ++it) {
    int ch = t + it * 256, r = ch >> 3, jc = ch & 7;
    rb[it] = *(const int4*)(xT + (size_t)r * 256 + jc * 8);
  }

  for (int ks = 0; ks < 4; ++ks) {
#pragma unroll
    for (int it = 0; it < 8; ++it) {
      int ch = t + it * 256, r = ch >> 3, jc = ch & 7;
      *(int4*)(lds + r * 128 + ((jc * 16) ^ ((r & 7) << 4))) = ra[it];
    }
#pragma unroll
    for (int it = 0; it < 2; ++it) {
      int ch = t + it * 256, r = ch >> 3, jc = ch & 7;
      *(int4*)(lds + 32768 + r * 128 + ((jc * 16) ^ ((r & 7) << 4))) = rb[it];
    }
    __syncthreads();
    if (ks < 3) {
#pragma unroll
      for (int it = 0; it < 8; ++it) {
        int ch = t + it * 256, r = ch >> 3, jc = ch & 7;
        ra[it] = *(const int4*)(Rst + r * 256 + (ks + 1) * 64 + jc * 8);
      }
#pragma unroll
      for (int it = 0; it < 2; ++it) {
        int ch = t + it * 256, r = ch >> 3, jc = ch & 7;
        rb[it] = *(const int4*)(xT + (size_t)r * 256 + (ks + 1) * 64 + jc * 8);
      }
    }
#pragma unroll
    for (int k2 = 0; k2 < 2; ++k2) {
      const int kb = k2 * 64 + lq * 16;
      bf16x8 bfr[4];
#pragma unroll
      for (int j = 0; j < 4; ++j) {
        int rn = j * 16 + lr;
        bfr[j] = *(const bf16x8*)(lds + 32768 + rn * 128 + (kb ^ ((rn & 7) << 4)));
      }
#pragma unroll
      for (int i = 0; i < 4; ++i) {
        int rc = wave * 64 + i * 16 + lr;
        bf16x8 af = *(const bf16x8*)(lds + rc * 128 + (kb ^ ((rc & 7) << 4)));
#pragma unroll
        for (int j = 0; j < 4; ++j)
          acc[i][j] = __builtin_amdgcn_mfma_f32_16x16x32_bf16(af, bfr[j], acc[i][j], 0, 0, 0);
      }
    }
    __syncthreads();
  }
  // stage tile to LDS bf16 [256 c][72] (pad keeps 16B align, spreads banks)
  ushort* po = (ushort*)lds;
#pragma unroll
  for (int i = 0; i < 4; ++i)
#pragma unroll
    for (int j = 0; j < 4; ++j)
#pragma unroll
      for (int rr = 0; rr < 4; ++rr) {
        int c_ = wave * 64 + i * 16 + lq * 4 + rr;
        po[c_ * 72 + j * 16 + lr] = f2bf(acc[i][j][rr]);
      }
  __syncthreads();
  const float* sarr = (const float*)(ws + WS_S) + b * 256;
  ushort* wyb = (ushort*)(ws + WS_WY) + (size_t)b * 1048576;  // [256][4096]
  float* sls = (float*)(lds + 36864);  // [512]: s1[256], s2[256] (outside po)
  const int rr_ = t >> 3, chk = t & 7;
#pragma unroll
  for (int pass = 0; pass < 8; ++pass) {
    int c = pass * 32 + rr_;
    int4 v = *(const int4*)(po + c * 72 + chk * 8);
    float sv = sarr[c];
    unsigned w[4] = {(unsigned)v.x, (unsigned)v.y, (unsigned)v.z, (unsigned)v.w};
    float s1 = 0.f, s2 = 0.f;
    unsigned o[4];
#pragma unroll
    for (int q = 0; q < 4; ++q) {
      float f0 = bf2f((ushort)(w[q] & 0xffffu)) + sv;
      float f1 = bf2f((ushort)(w[q] >> 16)) + sv;
      s1 += f0 + f1;
      s2 += f0 * f0 + f1 * f1;
      o[q] = (unsigned)f2bf(f0) | ((unsigned)f2bf(f1) << 16);
    }
    int4 ov;
    ov.x = (int)o[0]; ov.y = (int)o[1]; ov.z = (int)o[2]; ov.w = (int)o[3];
    *(int4*)(wyb + (size_t)c * 4096 + n0 + chk * 8) = ov;
    s1 += __shfl_xor(s1, 1); s1 += __shfl_xor(s1, 2); s1 += __shfl_xor(s1, 4);
    s2 += __shfl_xor(s2, 1); s2 += __shfl_xor(s2, 2); s2 += __shfl_xor(s2, 4);
    if (chk == 0) { sls[c] = s1; sls[256 + c] = s2; }
  }
  __syncthreads();
  // one coalesced partial-record store into this block's own xT slice (dead now)
  float2 pv;
  pv.x = sls[t];
  pv.y = sls[256 + t];
  float2* pslot = (float2*)((ushort*)(ws + WS_XT) + ((size_t)(b * 4096 + n0)) * 256);
  pslot[t] = pv;
}

// ------------- K4: reduce 1024 partial records -> gsum/gsq (16K atomics total) ---
__global__ __launch_bounds__(256) void kstat(char* __restrict__ ws) {
  const int t = threadIdx.x, blk = blockIdx.x;  // 32 blocks
  float a1 = 0.f, a2 = 0.f;
  const ushort* xTbase = (const ushort*)(ws + WS_XT);
  for (int i = 0; i < 32; ++i) {
    int s = blk * 32 + i;
    int b = s >> 6, nb = s & 63;
    const float2* p = (const float2*)(xTbase + ((size_t)(b * 4096 + nb * 64)) * 256);
    float2 v = p[t];
    a1 += v.x;
    a2 += v.y;
  }
  float* gsum = (float*)(ws + WS_SUM);
  atomicAdd(&gsum[t], a1);
  atomicAdd(&gsum[256 + t], a2);
}

// ------------- K5: out[b][c][n] = wy[c][n]*scale[c] + shift[c] + x[c][n] ---------
__global__ __launch_bounds__(256) void kout(
    const float* __restrict__ x, const float* __restrict__ gamma,
    const float* __restrict__ beta, const char* __restrict__ ws,
    float* __restrict__ out) {
  __shared__ float scaleL[256], shiftL[256];
  const int t = threadIdx.x;
  const int b = blockIdx.y, blk = blockIdx.x;
  {
    const float* gsum = (const float*)(ws + WS_SUM);
    float sm = gsum[t], sq = gsum[256 + t];
    float mean = sm * (1.0f / 65536.0f);
    float var = sq * (1.0f / 65536.0f) - mean * mean;
    float rs = rsqrtf(var + 1e-5f);
    float sc = gamma[t] * rs;
    scaleL[t] = sc;
    shiftL[t] = beta[t] - mean * sc;
  }
  __syncthreads();
  const ushort* wyb = (const ushort*)(ws + WS_WY) + (size_t)b * 1048576;
  const float* xb = x + (size_t)b * 1048576;
  float* ob = out + (size_t)b * 1048576;
#pragma unroll
  for (int it = 0; it < 8; ++it) {
    int idx = blk * 8192 + it * 1024 + t * 4;
    int c = idx >> 12;
    uint2 wv = *(const uint2*)(wyb + idx);
    float4 xv = *(const float4*)(xb + idx);
    float sc = scaleL[c], sh = shiftL[c];
    float4 ov;
    ov.x = bf2f((ushort)(wv.x & 0xffffu)) * sc + sh + xv.x;
    ov.y = bf2f((ushort)(wv.x >> 16)) * sc + sh + xv.y;
    ov.z = bf2f((ushort)(wv.y & 0xffffu)) * sc + sh + xv.z;
    ov.w = bf2f((ushort)(wv.y >> 16)) * sc + sh + xv.w;
    *(float4*)(ob + idx) = ov;
  }
}

extern "C" void kernel_launch(void* const* d_in, const int* in_sizes, int n_in,
                              void* d_out, int out_size, void* d_ws, size_t ws_size,
                              hipStream_t stream) {
  const float* x = (const float*)d_in[0];
  const float* thw = (const float*)d_in[1];
  const float* thb = (const float*)d_in[2];
  const float* phw = (const float*)d_in[3];
  const float* phb = (const float*)d_in[4];
  const float* gw = (const float*)d_in[5];
  const float* gb = (const float*)d_in[6];
  const float* www = (const float*)d_in[7];
  const float* wwb = (const float*)d_in[8];
  const float* gamma = (const float*)d_in[9];
  const float* beta = (const float*)d_in[10];
  char* ws = (char*)d_ws;
  float* out = (float*)d_out;

  kprep<<<dim3(4098), dim3(256), 0, stream>>>(x, phw, gw, ws);
  kconvpg<<<dim3(32, 16), dim3(256), 0, stream>>>(phb, gb, ws);
  kpg32<<<dim3(16, 16, 4), dim3(256), 0, stream>>>(ws);
  kmid<<<dim3(8, 16), dim3(256), 0, stream>>>(thw, thb, wwb, www, ws);
  kwyT<<<dim3(64, 16), dim3(256), 0, stream>>>(ws);
  kstat<<<dim3(32), dim3(256), 0, stream>>>(ws);
  kout<<<dim3(128, 16), dim3(256), 0, stream>>>(x, gamma, beta, ws, out);
}

// Round 10
// 374.436 us; speedup vs baseline: 1.2778x; 1.1568x over previous
//
#include <hip/hip_runtime.h>

#define DEVI static __device__ __forceinline__

typedef __attribute__((ext_vector_type(8))) short bf16x8;
typedef __attribute__((ext_vector_type(4))) float f32x4;

DEVI ushort f2bf(float f) {
  union { float f; unsigned u; } v; v.f = f;
  unsigned r = v.u + 0x7fffu + ((v.u >> 16) & 1u);
  return (ushort)(r >> 16);
}
DEVI float bf2f(ushort u) {
  union { unsigned u; float f; } v; v.u = ((unsigned)u) << 16;
  return v.f;
}

// B=16, C=256, CI=128, N=4096 (64x64), M=1024 (32x32)
// xT is GONE: both GEMM kernels transpose+pack x -> bf16 during LDS staging.
// ---- workspace layout (bytes); peak ~38 MB ----
#define WS_WCAT  0ull                      // bf16 [256][256] rows 0-127 phi_w, 128-255 g_w
#define WS_RST   131072ull                 // bf16 [16][256][256]
#define WS_S     2228224ull                // f32  [16][256]
#define WS_SUM   2244608ull                // f32  [256] sum + [256] sumsq
#define WS_PART  2246656ull                // f32  [1024 records][512] block stat partials
#define WS_WY    4343808ull                // bf16 [16][256][4096]  (NCHW-aligned)
// overlays inside WY (dead before kwyS writes WY):
#define WS_PHI   WS_WY                     // f32 [16][128][1024]
#define WS_G     (WS_WY + 8388608ull)      // f32 [16][128][1024]
#define WS_PG    (WS_WY + 16777216ull)     // f32 [4 kz][16][128][128] (K-split parts)

// ---------------- P: prep conv weights bf16, zero SUM ---------------------------
__global__ __launch_bounds__(256) void kprep2(
    const float* __restrict__ phw, const float* __restrict__ gww,
    char* __restrict__ ws) {
  const int bid = blockIdx.x, t = threadIdx.x;
  if (bid == 0) {
    ushort* Wcat = (ushort*)(ws + WS_WCAT);
    for (int idx = t; idx < 65536; idx += 256) {
      int ci = idx >> 8, c = idx & 255;
      float v = (ci < 128) ? phw[ci * 256 + c] : gww[(ci - 128) * 256 + c];
      Wcat[idx] = f2bf(v);
    }
  } else {
    float4 z = {0.f, 0.f, 0.f, 0.f};
    float4* st = (float4*)(ws + WS_SUM);
    if (t < 128) st[t] = z;
  }
}

// ------------- K1: phi/g conv (bf16 MFMA, x transposed in-kernel) + maxpool ------
__global__ __launch_bounds__(256) void kconvpg(
    const float* __restrict__ x, const float* __restrict__ phib,
    const float* __restrict__ gb, char* __restrict__ ws) {
  __shared__ __align__(16) char lds[49152];  // A: [128 n][64 c] bf16 16KB, B: [256 ci][64 c] 32KB
  const int t = threadIdx.x;
  const int b = blockIdx.y, nb = blockIdx.x;
  const int n0 = nb * 128;
  const int lane = t & 63, wave = t >> 6;
  const int lr = lane & 15, lq = lane >> 4;
  const ushort* Wc = (const ushort*)(ws + WS_WCAT);
  const float* xb = x + (size_t)b * 1048576 + n0;  // x[b][c][n], tile cols n0..n0+128

  f32x4 acc[8][4];
#pragma unroll
  for (int i = 0; i < 8; ++i)
#pragma unroll
    for (int j = 0; j < 4; ++j) acc[i][j] = (f32x4){0.f, 0.f, 0.f, 0.f};

  // per-ks staging regs: A from x (2 c-rows x 4 n-floats per it), B from Wcat
  float4 av0[4], av1[4];
  int4 rbv[8];
#pragma unroll
  for (int it = 0; it < 4; ++it) {
    int idx = t + it * 256;           // 0..1023 -> (c-pair p 0..31, n-quad q 0..31)
    int p = idx >> 5, q = idx & 31;
    av0[it] = *(const float4*)(xb + (size_t)(2 * p) * 4096 + q * 4);
    av1[it] = *(const float4*)(xb + (size_t)(2 * p + 1) * 4096 + q * 4);
  }
#pragma unroll
  for (int it = 0; it < 8; ++it) {
    int ch = t + it * 256, r = ch >> 3, jc = ch & 7;
    rbv[it] = *(const int4*)(Wc + r * 256 + jc * 8);
  }
  const int swz = (lr & 7) << 4;

  for (int ks = 0; ks < 4; ++ks) {
    // write A tile: transpose + pack bf16 pairs (c,c+1) -> [n][c] swizzled rows
#pragma unroll
    for (int it = 0; it < 4; ++it) {
      int idx = t + it * 256;
      int p = idx >> 5, q = idx & 31;
      float a0[4] = {av0[it].x, av0[it].y, av0[it].z, av0[it].w};
      float a1[4] = {av1[it].x, av1[it].y, av1[it].z, av1[it].w};
#pragma unroll
      for (int i = 0; i < 4; ++i) {
        int r = q * 4 + i;
        unsigned pk = (unsigned)f2bf(a0[i]) | ((unsigned)f2bf(a1[i]) << 16);
        int off = p * 4;
        int soff = (off & 15) | ((off & 0x70) ^ ((r & 7) << 4));
        *(unsigned*)(lds + r * 128 + soff) = pk;
      }
    }
#pragma unroll
    for (int it = 0; it < 8; ++it) {
      int ch = t + it * 256, r = ch >> 3, jc = ch & 7;
      *(int4*)(lds + 16384 + r * 128 + ((jc * 16) ^ ((r & 7) << 4))) = rbv[it];
    }
    __syncthreads();
    if (ks < 3) {
      const float* xn = xb + (size_t)(ks + 1) * 64 * 4096;
#pragma unroll
      for (int it = 0; it < 4; ++it) {
        int idx = t + it * 256;
        int p = idx >> 5, q = idx & 31;
        av0[it] = *(const float4*)(xn + (size_t)(2 * p) * 4096 + q * 4);
        av1[it] = *(const float4*)(xn + (size_t)(2 * p + 1) * 4096 + q * 4);
      }
#pragma unroll
      for (int it = 0; it < 8; ++it) {
        int ch = t + it * 256, r = ch >> 3, jc = ch & 7;
        rbv[it] = *(const int4*)(Wc + r * 256 + (ks + 1) * 64 + jc * 8);
      }
    }
#pragma unroll
    for (int k2 = 0; k2 < 2; ++k2) {
      const int kb = k2 * 64 + lq * 16;
      bf16x8 bfr[4];
#pragma unroll
      for (int j = 0; j < 4; ++j) {
        int bc = wave * 64 + j * 16 + lr;
        bfr[j] = *(const bf16x8*)(lds + 16384 + bc * 128 + (kb ^ swz));
      }
#pragma unroll
      for (int i = 0; i < 8; ++i) {
        int arw = i * 16 + lr;
        bf16x8 af = *(const bf16x8*)(lds + arw * 128 + (kb ^ swz));
#pragma unroll
        for (int j = 0; j < 4; ++j)
          acc[i][j] = __builtin_amdgcn_mfma_f32_16x16x32_bf16(af, bfr[j], acc[i][j], 0, 0, 0);
      }
    }
    __syncthreads();
  }
  // epilogue: pool (r,r+1)x(r+64,r+65) + bias -> LDS [256ci][36] f32, coalesced store
  float* pool = (float*)lds;
#pragma unroll
  for (int j = 0; j < 4; ++j) {
    int cir = wave * 64 + j * 16 + lr;
    float bias = (cir < 128) ? phib[cir] : gb[cir - 128];
#pragma unroll
    for (int i = 0; i < 4; ++i) {
      f32x4 lo = acc[i][j], hi = acc[i + 4][j];
      float m0 = fmaxf(fmaxf(lo[0], lo[1]), fmaxf(hi[0], hi[1])) + bias;
      float m1 = fmaxf(fmaxf(lo[2], lo[3]), fmaxf(hi[2], hi[3])) + bias;
      pool[cir * 36 + i * 8 + lq * 2] = m0;
      pool[cir * 36 + i * 8 + lq * 2 + 1] = m1;
    }
  }
  __syncthreads();
  const int rr_ = t >> 3, chk = t & 7;
#pragma unroll
  for (int pass = 0; pass < 8; ++pass) {
    int ci = pass * 32 + rr_;
    float4 v = *(const float4*)(pool + ci * 36 + chk * 4);
    float* dst = (ci < 128)
        ? ((float*)(ws + WS_PHI) + ((size_t)(b * 128 + ci)) * 1024)
        : ((float*)(ws + WS_G) + ((size_t)(b * 128 + ci - 128)) * 1024);
    *(float4*)(dst + nb * 32 + chk * 4) = v;
  }
}

// ------------- K2a: PG_part[kz][b][ci][cj] = sum_m(kz slice) phi*g  (no atomics) -
__global__ __launch_bounds__(256) void kpg32(char* __restrict__ ws) {
  __shared__ float lphi[32 * 65];
  __shared__ float lgd[32 * 65];
  const int t = threadIdx.x, b = blockIdx.y, kz = blockIdx.z;
  const int cib = blockIdx.x >> 2, cjb = blockIdx.x & 3;
  const int ci_l = t >> 5, cj_l = t & 31;
  const float* phi = (const float*)(ws + WS_PHI) + ((size_t)(b * 128 + cib * 32)) * 1024;
  const float* gg = (const float*)(ws + WS_G) + ((size_t)(b * 128 + cjb * 32)) * 1024;
  float acc[4] = {0.f, 0.f, 0.f, 0.f};
  for (int kc = kz * 4; kc < kz * 4 + 4; ++kc) {
#pragma unroll
    for (int it = 0; it < 8; ++it) {
      int fi = t + it * 256;
      int r = fi >> 6, c = fi & 63;
      lphi[r * 65 + c] = phi[(size_t)r * 1024 + kc * 64 + c];
      lgd[r * 65 + c] = gg[(size_t)r * 1024 + kc * 64 + c];
    }
    __syncthreads();
#pragma unroll 8
    for (int k = 0; k < 64; ++k) {
      float gv = lgd[cj_l * 65 + k];
#pragma unroll
      for (int p = 0; p < 4; ++p)
        acc[p] += lphi[(ci_l * 4 + p) * 65 + k] * gv;
    }
    __syncthreads();
  }
  float* PG = (float*)(ws + WS_PG) + (size_t)kz * 262144 + (size_t)b * 16384;
#pragma unroll
  for (int p = 0; p < 4; ++p)
    PG[(cib * 32 + ci_l * 4 + p) * 128 + cjb * 32 + cj_l] = acc[p];
}

// ------------- K2b: fused Qt -> Rst -> s, fp32 VALU; sums the 4 PG parts ---------
__global__ __launch_bounds__(256) void kmid(
    const float* __restrict__ thw, const float* __restrict__ thb,
    const float* __restrict__ wbias, const float* __restrict__ www,
    char* __restrict__ ws) {
  __shared__ __align__(16) char smid[49920];
  float* PGc = (float*)smid;             // [128][33] (phase 1)
  float* Wws = (float*)(smid + 16896);   // [32][129] (phase 1)
  float* Qts = (float*)(smid + 33408);   // [32][129]
  float* thws = (float*)smid;            // [128][65] (phase 2, overlays PGc+Wws)
  const int t = threadIdx.x, b = blockIdx.y, cblk = blockIdx.x;
  const int c_l = t >> 3, q = t & 7;
  const float* PG0 = (const float*)(ws + WS_PG) + (size_t)b * 16384;

#pragma unroll
  for (int it = 0; it < 16; ++it) {
    int fi = t + it * 256;
    int r = fi >> 7, j = fi & 127;
    Wws[r * 129 + j] = www[(cblk * 32 + r) * 128 + j];
  }
  float qacc[16];
#pragma unroll
  for (int i = 0; i < 16; ++i) qacc[i] = 0.f;

  for (int jc = 0; jc < 4; ++jc) {
#pragma unroll
    for (int it = 0; it < 16; ++it) {
      int fi = t + it * 256;
      int i = fi >> 5, jl = fi & 31;
      int idx = i * 128 + jc * 32 + jl;
      PGc[i * 33 + jl] = PG0[idx] + PG0[262144 + idx] + PG0[524288 + idx] + PG0[786432 + idx];
    }
    __syncthreads();
#pragma unroll
    for (int iq = 0; iq < 16; ++iq) {
      int i = iq * 8 + q;
      float a = 0.f;
#pragma unroll 8
      for (int jl = 0; jl < 32; ++jl)
        a += Wws[c_l * 129 + jc * 32 + jl] * PGc[i * 33 + jl];
      qacc[iq] += a;
    }
    __syncthreads();
  }
  const float inv = 1.0f / 1024.0f;
#pragma unroll
  for (int iq = 0; iq < 16; ++iq) Qts[c_l * 129 + iq * 8 + q] = qacc[iq] * inv;
  __syncthreads();
  if (t < 32) {
    float sv = wbias[cblk * 32 + t];
    for (int i = 0; i < 128; ++i) sv += thb[i] * Qts[t * 129 + i];
    ((float*)(ws + WS_S))[b * 256 + cblk * 32 + t] = sv;
  }
  ushort* Rstb = (ushort*)(ws + WS_RST) + (size_t)b * 65536;
  for (int cpc = 0; cpc < 4; ++cpc) {
#pragma unroll
    for (int it = 0; it < 32; ++it) {
      int fi = t + it * 256;
      int i = fi >> 6, cp = fi & 63;
      thws[i * 65 + cp] = thw[i * 256 + cpc * 64 + cp];
    }
    __syncthreads();
#pragma unroll
    for (int k = 0; k < 8; ++k) {
      int cpl = q * 8 + k;
      float a = 0.f;
#pragma unroll 8
      for (int i = 0; i < 128; ++i)
        a += Qts[c_l * 129 + i] * thws[i * 65 + cpl];
      Rstb[(cblk * 32 + c_l) * 256 + cpc * 64 + cpl] = f2bf(a);
    }
    __syncthreads();
  }
}

// ------------- K3: wy[b][c][n] = Rst[c][:].x^T[n][:] + s[c]  (x transposed here) -
// coalesced [c][n] store; per-block stats -> one float2[256] record (no atomics)
__global__ __launch_bounds__(256) void kwyS(
    const float* __restrict__ x, char* __restrict__ ws) {
  __shared__ __align__(16) char lds[40960];  // loop: Rst 32KB + xtile 8KB; epi: po 36KB + sls 2KB
  const int t = threadIdx.x;
  const int b = blockIdx.y, nb = blockIdx.x;  // nb 0..63
  const int n0 = nb * 64;
  const int lane = t & 63, wave = t >> 6;
  const int lr = lane & 15, lq = lane >> 4;
  const float* xb = x + (size_t)b * 1048576 + n0;  // x[b][c][n], cols n0..n0+64
  const ushort* Rst = (const ushort*)(ws + WS_RST) + (size_t)b * 65536;

  f32x4 acc[4][4];  // i: c-tile (wave*64+i*16), j: n-tile (j*16)
#pragma unroll
  for (int i = 0; i < 4; ++i)
#pragma unroll
    for (int j = 0; j < 4; ++j) acc[i][j] = (f32x4){0.f, 0.f, 0.f, 0.f};

  int4 ra[8];
  float4 xv0[2], xv1[2];
#pragma unroll
  for (int it = 0; it < 8; ++it) {
    int ch = t + it * 256, r = ch >> 3, jc = ch & 7;
    ra[it] = *(const int4*)(Rst + r * 256 + jc * 8);
  }
#pragma unroll
  for (int it = 0; it < 2; ++it) {
    int idx = t + it * 256;          // 0..511 -> (c-pair p 0..31, n-quad q 0..15)
    int p = idx >> 4, q = idx & 15;
    xv0[it] = *(const float4*)(xb + (size_t)(2 * p) * 4096 + q * 4);
    xv1[it] = *(const float4*)(xb + (size_t)(2 * p + 1) * 4096 + q * 4);
  }

  for (int ks = 0; ks < 4; ++ks) {
#pragma unroll
    for (int it = 0; it < 8; ++it) {
      int ch = t + it * 256, r = ch >> 3, jc = ch & 7;
      *(int4*)(lds + r * 128 + ((jc * 16) ^ ((r & 7) << 4))) = ra[it];
    }
#pragma unroll
    for (int it = 0; it < 2; ++it) {
      int idx = t + it * 256;
      int p = idx >> 4, q = idx & 15;
      float a0[4] = {xv0[it].x, xv0[it].y, xv0[it].z, xv0[it].w};
      float a1[4] = {xv1[it].x, xv1[it].y, xv1[it].z, xv1[it].w};
#pragma unroll
      for (int i = 0; i < 4; ++i) {
        int r = q * 4 + i;
        unsigned pk = (unsigned)f2bf(a0[i]) | ((unsigned)f2bf(a1[i]) << 16);
        int off = p * 4;
        int soff = (off & 15) | ((off & 0x70) ^ ((r & 7) << 4));
        *(unsigned*)(lds + 32768 + r * 128 + soff) = pk;
      }
    }
    __syncthreads();
    if (ks < 3) {
      const float* xn = xb + (size_t)(ks + 1) * 64 * 4096;
#pragma unroll
      for (int it = 0; it < 8; ++it) {
        int ch = t + it * 256, r = ch >> 3, jc = ch & 7;
        ra[it] = *(const int4*)(Rst + r * 256 + (ks + 1) * 64 + jc * 8);
      }
#pragma unroll
      for (int it = 0; it < 2; ++it) {
        int idx = t + it * 256;
        int p = idx >> 4, q = idx & 15;
        xv0[it] = *(const float4*)(xn + (size_t)(2 * p) * 4096 + q * 4);
        xv1[it] = *(const float4*)(xn + (size_t)(2 * p + 1) * 4096 + q * 4);
      }
    }
#pragma unroll
    for (int k2 = 0; k2 < 2; ++k2) {
      const int kb = k2 * 64 + lq * 16;
      bf16x8 bfr[4];
#pragma unroll
      for (int j = 0; j < 4; ++j) {
        int rn = j * 16 + lr;
        bfr[j] = *(const bf16x8*)(lds + 32768 + rn * 128 + (kb ^ ((rn & 7) << 4)));
      }
#pragma unroll
      for (int i = 0; i < 4; ++i) {
        int rc = wave * 64 + i * 16 + lr;
        bf16x8 af = *(const bf16x8*)(lds + rc * 128 + (kb ^ ((rc & 7) << 4)));
#pragma unroll
        for (int j = 0; j < 4; ++j)
          acc[i][j] = __builtin_amdgcn_mfma_f32_16x16x32_bf16(af, bfr[j], acc[i][j], 0, 0, 0);
      }
    }
    __syncthreads();
  }
  // stage tile to LDS bf16 [256 c][72]
  ushort* po = (ushort*)lds;
#pragma unroll
  for (int i = 0; i < 4; ++i)
#pragma unroll
    for (int j = 0; j < 4; ++j)
#pragma unroll
      for (int rr = 0; rr < 4; ++rr) {
        int c_ = wave * 64 + i * 16 + lq * 4 + rr;
        po[c_ * 72 + j * 16 + lr] = f2bf(acc[i][j][rr]);
      }
  __syncthreads();
  const float* sarr = (const float*)(ws + WS_S) + b * 256;
  ushort* wyb = (ushort*)(ws + WS_WY) + (size_t)b * 1048576;  // [256][4096]
  float* sls = (float*)(lds + 36864);  // [512]: s1[256], s2[256]
  const int rr_ = t >> 3, chk = t & 7;
#pragma unroll
  for (int pass = 0; pass < 8; ++pass) {
    int c = pass * 32 + rr_;
    int4 v = *(const int4*)(po + c * 72 + chk * 8);
    float sv = sarr[c];
    unsigned w[4] = {(unsigned)v.x, (unsigned)v.y, (unsigned)v.z, (unsigned)v.w};
    float s1 = 0.f, s2 = 0.f;
    unsigned o[4];
#pragma unroll
    for (int q = 0; q < 4; ++q) {
      float f0 = bf2f((ushort)(w[q] & 0xffffu)) + sv;
      float f1 = bf2f((ushort)(w[q] >> 16)) + sv;
      s1 += f0 + f1;
      s2 += f0 * f0 + f1 * f1;
      o[q] = (unsigned)f2bf(f0) | ((unsigned)f2bf(f1) << 16);
    }
    int4 ov;
    ov.x = (int)o[0]; ov.y = (int)o[1]; ov.z = (int)o[2]; ov.w = (int)o[3];
    *(int4*)(wyb + (size_t)c * 4096 + n0 + chk * 8) = ov;
    s1 += __shfl_xor(s1, 1); s1 += __shfl_xor(s1, 2); s1 += __shfl_xor(s1, 4);
    s2 += __shfl_xor(s2, 1); s2 += __shfl_xor(s2, 2); s2 += __shfl_xor(s2, 4);
    if (chk == 0) { sls[c] = s1; sls[256 + c] = s2; }
  }
  __syncthreads();
  float2 pv;
  pv.x = sls[t];
  pv.y = sls[256 + t];
  float2* pslot = (float2*)(ws + WS_PART) + (size_t)(b * 64 + nb) * 256;
  pslot[t] = pv;
}

// ------------- K4: reduce 1024 partial records -> gsum/gsq ----------------------
__global__ __launch_bounds__(256) void kstat(char* __restrict__ ws) {
  const int t = threadIdx.x, blk = blockIdx.x;  // 32 blocks
  float a1 = 0.f, a2 = 0.f;
  for (int i = 0; i < 32; ++i) {
    const float2* p = (const float2*)(ws + WS_PART) + (size_t)(blk * 32 + i) * 256;
    float2 v = p[t];
    a1 += v.x;
    a2 += v.y;
  }
  float* gsum = (float*)(ws + WS_SUM);
  atomicAdd(&gsum[t], a1);
  atomicAdd(&gsum[256 + t], a2);
}

// ------------- K5: out[b][c][n] = wy[c][n]*scale[c] + shift[c] + x[c][n] ---------
__global__ __launch_bounds__(256) void kout(
    const float* __restrict__ x, const float* __restrict__ gamma,
    const float* __restrict__ beta, const char* __restrict__ ws,
    float* __restrict__ out) {
  __shared__ float scaleL[256], shiftL[256];
  const int t = threadIdx.x;
  const int b = blockIdx.y, blk = blockIdx.x;
  {
    const float* gsum = (const float*)(ws + WS_SUM);
    float sm = gsum[t], sq = gsum[256 + t];
    float mean = sm * (1.0f / 65536.0f);
    float var = sq * (1.0f / 65536.0f) - mean * mean;
    float rs = rsqrtf(var + 1e-5f);
    float sc = gamma[t] * rs;
    scaleL[t] = sc;
    shiftL[t] = beta[t] - mean * sc;
  }
  __syncthreads();
  const ushort* wyb = (const ushort*)(ws + WS_WY) + (size_t)b * 1048576;
  const float* xb = x + (size_t)b * 1048576;
  float* ob = out + (size_t)b * 1048576;
#pragma unroll
  for (int it = 0; it < 8; ++it) {
    int idx = blk * 8192 + it * 1024 + t * 4;
    int c = idx >> 12;
    uint2 wv = *(const uint2*)(wyb + idx);
    float4 xv = *(const float4*)(xb + idx);
    float sc = scaleL[c], sh = shiftL[c];
    float4 ov;
    ov.x = bf2f((ushort)(wv.x & 0xffffu)) * sc + sh + xv.x;
    ov.y = bf2f((ushort)(wv.x >> 16)) * sc + sh + xv.y;
    ov.z = bf2f((ushort)(wv.y & 0xffffu)) * sc + sh + xv.z;
    ov.w = bf2f((ushort)(wv.y >> 16)) * sc + sh + xv.w;
    *(float4*)(ob + idx) = ov;
  }
}

extern "C" void kernel_launch(void* const* d_in, const int* in_sizes, int n_in,
                              void* d_out, int out_size, void* d_ws, size_t ws_size,
                              hipStream_t stream) {
  const float* x = (const float*)d_in[0];
  const float* thw = (const float*)d_in[1];
  const float* thb = (const float*)d_in[2];
  const float* phw = (const float*)d_in[3];
  const float* phb = (const float*)d_in[4];
  const float* gw = (const float*)d_in[5];
  const float* gb = (const float*)d_in[6];
  const float* www = (const float*)d_in[7];
  const float* wwb = (const float*)d_in[8];
  const float* gamma = (const float*)d_in[9];
  const float* beta = (const float*)d_in[10];
  char* ws = (char*)d_ws;
  float* out = (float*)d_out;

  kprep2<<<dim3(2), dim3(256), 0, stream>>>(phw, gw, ws);
  kconvpg<<<dim3(32, 16), dim3(256), 0, stream>>>(x, phb, gb, ws);
  kpg32<<<dim3(16, 16, 4), dim3(256), 0, stream>>>(ws);
  kmid<<<dim3(8, 16), dim3(256), 0, stream>>>(thw, thb, wwb, www, ws);
  kwyS<<<dim3(64, 16), dim3(256), 0, stream>>>(x, ws);
  kstat<<<dim3(32), dim3(256), 0, stream>>>(ws);
  kout<<<dim3(128, 16), dim3(256), 0, stream>>>(x, gamma, beta, ws, out);
}